// Round 17
// baseline (64.103 us; speedup 1.0000x reference)
//
#include <hip/hip_runtime.h>
#include <math.h>

// SSIM (16,3,512,512) fp32, 11x11 separable Gaussian, VALID -> per-batch mean [16].
//
// Round-17: round-16 (59.4us) with two changes:
//  1) NSLOT 11 -> 8: LDS 53.8 -> 38.9 KB so 3 blocks/CU fit with margin
//     (A/B test: was the 53.8KB allocation what pinned occupancy at 2/CU?).
//     Slot index (klin & 7) is runtime LDS address math (legal; only register
//     arrays need static indices). Ring hs[k] stays static.
//  2) wv[] array dropped; weights splatted inline from kernarg so ISel can
//     keep them in SGPRs (VOP3P allows one SGPR operand w/ op_sel broadcast).
//  - Each wave owns a 128-output-col strip (2 cols/thread) and stages its own
//    rows via global_load_lds; per-wave vmcnt(24) is the only synchronization.
//  - Packed fp32 math (v_pk_fma_f32 via __builtin_elementwise_fma).
//  - 255x scaling cancels: C1 = 1e-4, C2 = 9e-4 on [0,1] data.

#define WSZ 11
#define IMG 512
#define OSZ 502
#define NT  256
#define CH_OUT 32
#define NCHUNK 16        // 16*32 >= 502
#define NSLOT 8          // LDS row-ring depth (power of 2)
#define LA 6             // lookahead rows

struct WinArg { float w[WSZ]; };

typedef float f2 __attribute__((ext_vector_type(2)));
typedef float f4v __attribute__((ext_vector_type(4)));

typedef const __attribute__((address_space(1))) unsigned int* gp_t;
typedef __attribute__((address_space(3))) unsigned int* sp_t;

#define C1V 1.0e-4f
#define C2V 9.0e-4f

__device__ __forceinline__ void pkfma(f2& acc, float w, f2 b) {
    f2 wv; wv.x = w; wv.y = w;                    // splat (op_sel broadcastable)
    acc = __builtin_elementwise_fma(wv, b, acc);  // v_pk_fma_f32
}

__global__ __launch_bounds__(NT, 3) void ssim_pk8(
    const float* __restrict__ rawp, const float* __restrict__ dstp,
    float* __restrict__ out, WinArg wa, float inv_n)
{
    // waves 0-2: 8 slots x 80 float4 (640 f4 each); wave 3: 8 x 64 (512 f4)
    __shared__ f4v srow[2432];               // 38912 B
    __shared__ float wred[NT / 64];

    const int tid  = threadIdx.x;
    const int lane = tid & 63;
    const int wave = tid >> 6;
    const int chunk = blockIdx.x;
    const int img   = blockIdx.y;

    const int o0    = chunk * CH_OUT;
    const int olim  = min(o0 + CH_OUT, OSZ);
    const int rlast = min(o0 + CH_OUT + WSZ - 2, IMG - 1);
    const int NR    = rlast - o0 + 1;        // 42 (32 for last chunk)

    const bool w3     = (wave == 3);
    const int  nch    = w3 ? 4 : 5;          // DMA chunks per row (wave-uniform)
    const int  slotf4 = w3 ? 64 : 80;        // float4 per slot (wave-uniform)
    f4v* region = srow + wave * 640;         // wave 3 -> 1920, uses 512 f4
    const int  rl     = (w3 && lane > 58) ? 58 : lane;   // read clamp
    const bool active = !(w3 && lane > 58);

    const size_t ibase = (size_t)img * (size_t)(IMG * IMG);
    // lane parity -> channel; (lane>>1) -> col within 32-col chunk
    const float* lane_base = ((lane & 1) ? dstp : rawp) + ibase
                           + (size_t)(wave * 128 + (lane >> 1));

#define STAGE(ROW, SLOT)                                                       \
    {                                                                          \
        const float* _s = lane_base + (size_t)(ROW) * IMG;                     \
        float* _d = (float*)(region + (SLOT) * slotf4);                        \
        _Pragma("unroll")                                                      \
        for (int _c = 0; _c < 5; ++_c) {                                       \
            if (_c < nch)                                                      \
                __builtin_amdgcn_global_load_lds(                              \
                    (gp_t)(const void*)(_s + 32 * _c),                         \
                    (sp_t)(void*)(_d + 64 * _c), 4, 0, 0);                     \
        }                                                                      \
    }

    f2 hs12[WSZ][2];                         // ring: [slot][col] {mu_r, mu_d}
    f2 hs34[WSZ][2];                         // ring: [slot][col] {E_rr+dd, E_rd}
    float acc = 0.0f;

    // prologue: rows 0..LA-1 in flight (slots 0..5 == row&7)
#pragma unroll
    for (int r = 0; r < LA; ++r) STAGE(o0 + r, r)

#pragma unroll 1
    for (int rr = 0; rr < NR; rr += WSZ) {
#pragma unroll
        for (int k = 0; k < WSZ; ++k) {
            const int klin = rr + k;
            if (klin < NR) {                 // block-uniform
                // stage row klin+LA (clamped tail restage lands in dead slot)
                {
                    int rs = klin + LA; if (rs > NR - 1) rs = NR - 1;
                    STAGE(o0 + rs, (klin + LA) & (NSLOT - 1))
                }
                // per-wave wait: guarantees row klin's loads complete
                asm volatile("s_waitcnt vmcnt(24)" ::: "memory");

                f4v q[6];
                {
                    const f4v* rp = region + (klin & (NSLOT - 1)) * slotf4 + rl;
#pragma unroll
                    for (int j = 0; j < 6; ++j) q[j] = rp[j];
                }

                // ---- H-pass, 2 cols, packed channels ----
                f2 s12a = {0.f, 0.f}, s34a = {0.f, 0.f};
                f2 s12b = {0.f, 0.f}, s34b = {0.f, 0.f};
#pragma unroll
                for (int e = 0; e < 12; ++e) {
                    const f2 rd = (e & 1) ? q[e >> 1].zw : q[e >> 1].xy;
                    const f2 rr2 = rd * rd;                // v_pk_mul_f32
                    f2 sp;                                 // (r^2+d^2, r*d)
                    sp.x = rr2.x + rr2.y;
                    sp.y = rd.x * rd.y;
                    if (e < 11) {            // col a tap e
                        pkfma(s12a, wa.w[e], rd);
                        pkfma(s34a, wa.w[e], sp);
                    }
                    if (e >= 1) {            // col b tap e-1
                        pkfma(s12b, wa.w[e - 1], rd);
                        pkfma(s34b, wa.w[e - 1], sp);
                    }
                }
                hs12[k][0] = s12a; hs34[k][0] = s34a;
                hs12[k][1] = s12b; hs34[k][1] = s34b;

                // ---- V-pass + SSIM ----
                const int o = o0 + klin - (WSZ - 1);
                if (klin >= WSZ - 1 && o < olim && active) {
                    f2 m12a = {0.f, 0.f}, m34a = {0.f, 0.f};
                    f2 m12b = {0.f, 0.f}, m34b = {0.f, 0.f};
#pragma unroll
                    for (int i = 0; i < WSZ; ++i) {
                        const int s = (k + 1 + i) % WSZ;   // static after unroll
                        pkfma(m12a, wa.w[i], hs12[s][0]);
                        pkfma(m34a, wa.w[i], hs34[s][0]);
                        pkfma(m12b, wa.w[i], hs12[s][1]);
                        pkfma(m34b, wa.w[i], hs34[s][1]);
                    }
                    {
                        const float m1 = m12a.x, m2 = m12a.y;
                        const float m3 = m34a.x, m4 = m34a.y;
                        const float q1 = m1 * m1, q2 = m2 * m2, mm = m1 * m2;
                        const float num = (2.f * mm + C1V) * (2.f * (m4 - mm) + C2V);
                        const float den = (q1 + q2 + C1V) * (((m3 - q1) - q2) + C2V);
                        acc += num * __builtin_amdgcn_rcpf(den);
                    }
                    {
                        const float m1 = m12b.x, m2 = m12b.y;
                        const float m3 = m34b.x, m4 = m34b.y;
                        const float q1 = m1 * m1, q2 = m2 * m2, mm = m1 * m2;
                        const float num = (2.f * mm + C1V) * (2.f * (m4 - mm) + C2V);
                        const float den = (q1 + q2 + C1V) * (((m3 - q1) - q2) + C2V);
                        acc += num * __builtin_amdgcn_rcpf(den);
                    }
                }
            }
        }
    }
#undef STAGE

    // ---- block reduction -> one atomicAdd per block ----
#pragma unroll
    for (int off = 32; off > 0; off >>= 1) acc += __shfl_down(acc, off, 64);
    if (lane == 0) wred[wave] = acc;
    __syncthreads();
    if (tid == 0) {
        const float tot = (wred[0] + wred[1]) + (wred[2] + wred[3]);
        atomicAdd(out + img / 3, tot * inv_n);
    }
}

extern "C" void kernel_launch(void* const* d_in, const int* in_sizes, int n_in,
                              void* d_out, int out_size, void* d_ws, size_t ws_size,
                              hipStream_t stream) {
    const float* raw = (const float*)d_in[0];
    const float* dst = (const float*)d_in[1];
    float* out = (float*)d_out;

    hipMemsetAsync(out, 0, (size_t)out_size * sizeof(float), stream);

    WinArg wa;
    double g[WSZ], s = 0.0;
    for (int i = 0; i < WSZ; ++i) {
        double ax = (double)i - (double)(WSZ - 1) / 2.0;
        g[i] = exp(-(ax * ax) / (2.0 * 1.5 * 1.5));
        s += g[i];
    }
    for (int i = 0; i < WSZ; ++i) wa.w[i] = (float)(g[i] / s);

    const float inv_n = (float)(1.0 / (3.0 * (double)OSZ * (double)OSZ));

    dim3 grid(NCHUNK, 48);
    ssim_pk8<<<grid, NT, 0, stream>>>(raw, dst, out, wa, inv_n);
}

// Round 18
// 62.296 us; speedup vs baseline: 1.0290x; 1.0290x over previous
//
#include <hip/hip_runtime.h>
#include <math.h>

// SSIM (16,3,512,512) fp32, 11x11 separable Gaussian, VALID -> per-batch mean [16].
//
// Round-18: round-16 (59.4us) + 2-row inner steps for ILP.
//  - Occupancy is pinned at ~2 waves/SIMD by the register allocator (R17 A/B
//    proved LDS is not the blocker), so this round buys ILP instead of TLP:
//    each step processes TWO rows with one vmcnt wait and one ds_read burst;
//    the two H/V chains are independent and interleave in the scheduler.
//  - NSLOT = ring depth = 12 (even): outer step 12 rows = 6 double-steps,
//    all LDS-slot and ring indices compile-time static.
//  - __launch_bounds__(256,2): full 256-reg budget, no spill (~190 live).
//  - Packed fp32 throughout (v_pk_fma_f32 via __builtin_elementwise_fma).
//  - Each wave owns a 128-output-col strip (2 cols/thread) and stages its own
//    rows via global_load_lds; per-wave counted vmcnt is the only sync.
//  - 255x scaling cancels: C1 = 1e-4, C2 = 9e-4 on [0,1] data.

#define WSZ 11
#define IMG 512
#define OSZ 502
#define NT  256
#define CH_OUT 32
#define NCHUNK 16        // 16*32 >= 502
#define NS 12            // LDS slots == register-ring depth (even)
#define LA 6             // lookahead rows

struct WinArg { float w[WSZ]; };

typedef float f2 __attribute__((ext_vector_type(2)));
typedef float f4v __attribute__((ext_vector_type(4)));

typedef const __attribute__((address_space(1))) unsigned int* gp_t;
typedef __attribute__((address_space(3))) unsigned int* sp_t;

#define C1V 1.0e-4f
#define C2V 9.0e-4f

__device__ __forceinline__ void pkfma(f2& acc, f2 a, f2 b) {
    acc = __builtin_elementwise_fma(a, b, acc);   // v_pk_fma_f32
}

__global__ __launch_bounds__(NT, 2) void ssim_ilp2(
    const float* __restrict__ rawp, const float* __restrict__ dstp,
    float* __restrict__ out, WinArg wa, float inv_n)
{
    // waves 0-2: 12 slots x 80 float4 (960 f4 each); wave 3: 12 x 64 (768 f4)
    __shared__ f4v srow[3648];               // 58368 B -> 2 blocks/CU
    __shared__ float wred[NT / 64];

    const int tid  = threadIdx.x;
    const int lane = tid & 63;
    const int wave = tid >> 6;
    const int chunk = blockIdx.x;
    const int img   = blockIdx.y;

    const int o0    = chunk * CH_OUT;
    const int olim  = min(o0 + CH_OUT, OSZ);
    const int rlast = min(o0 + CH_OUT + WSZ - 2, IMG - 1);
    const int NR    = rlast - o0 + 1;        // 42 (32 for last chunk), even

    const bool w3     = (wave == 3);
    const int  nch    = w3 ? 4 : 5;          // DMA chunks per row (wave-uniform)
    const int  slotf4 = w3 ? 64 : 80;        // float4 per slot (wave-uniform)
    f4v* region = srow + wave * 960;         // wave 3 -> 2880, uses 768 f4
    const int  rl     = (w3 && lane > 58) ? 58 : lane;   // read clamp
    const bool active = !(w3 && lane > 58);

    const size_t ibase = (size_t)img * (size_t)(IMG * IMG);
    // lane parity -> channel; (lane>>1) -> col within 32-col chunk
    const float* lane_base = ((lane & 1) ? dstp : rawp) + ibase
                           + (size_t)(wave * 128 + (lane >> 1));

    // packed weights
    f2 wv[WSZ];
#pragma unroll
    for (int j = 0; j < WSZ; ++j) { wv[j].x = wa.w[j]; wv[j].y = wa.w[j]; }

#define STAGE(ROW, SLOT)                                                       \
    {                                                                          \
        const float* _s = lane_base + (size_t)(ROW) * IMG;                     \
        float* _d = (float*)(region + (SLOT) * slotf4);                        \
        _Pragma("unroll")                                                      \
        for (int _c = 0; _c < 5; ++_c) {                                       \
            if (_c < nch)                                                      \
                __builtin_amdgcn_global_load_lds(                              \
                    (gp_t)(const void*)(_s + 32 * _c),                         \
                    (sp_t)(void*)(_d + 64 * _c), 4, 0, 0);                     \
        }                                                                      \
    }

    // H-pass on window QQ -> ring slot KS (2 cols, element-shared, packed)
#define HPASS(QQ, KS)                                                          \
    {                                                                          \
        f2 s12a = {0.f, 0.f}, s34a = {0.f, 0.f};                               \
        f2 s12b = {0.f, 0.f}, s34b = {0.f, 0.f};                               \
        _Pragma("unroll")                                                      \
        for (int e = 0; e < 12; ++e) {                                         \
            const f2 rd = (e & 1) ? QQ[e >> 1].zw : QQ[e >> 1].xy;             \
            const f2 rr2 = rd * rd;                                            \
            f2 sp;                                                             \
            sp.x = rr2.x + rr2.y;                                              \
            sp.y = rd.x * rd.y;                                                \
            if (e < 11) { pkfma(s12a, wv[e], rd); pkfma(s34a, wv[e], sp); }    \
            if (e >= 1) { pkfma(s12b, wv[e-1], rd); pkfma(s34b, wv[e-1], sp); }\
        }                                                                      \
        hs12[KS][0] = s12a; hs34[KS][0] = s34a;                                \
        hs12[KS][1] = s12b; hs34[KS][1] = s34b;                                \
    }

    // V-pass + SSIM for output row fed by ring rows starting at slot KOFF
#define VPASS(KOFF)                                                            \
    {                                                                          \
        f2 m12a = {0.f, 0.f}, m34a = {0.f, 0.f};                               \
        f2 m12b = {0.f, 0.f}, m34b = {0.f, 0.f};                               \
        _Pragma("unroll")                                                      \
        for (int i = 0; i < WSZ; ++i) {                                        \
            const int s = ((KOFF) + i) % NS;                                   \
            pkfma(m12a, wv[i], hs12[s][0]);                                    \
            pkfma(m34a, wv[i], hs34[s][0]);                                    \
            pkfma(m12b, wv[i], hs12[s][1]);                                    \
            pkfma(m34b, wv[i], hs34[s][1]);                                    \
        }                                                                      \
        {                                                                      \
            const float m1 = m12a.x, m2 = m12a.y;                              \
            const float m3 = m34a.x, m4 = m34a.y;                              \
            const float q1 = m1 * m1, q2 = m2 * m2, mm = m1 * m2;              \
            const float num = (2.f * mm + C1V) * (2.f * (m4 - mm) + C2V);      \
            const float den = (q1 + q2 + C1V) * (((m3 - q1) - q2) + C2V);      \
            acc += num * __builtin_amdgcn_rcpf(den);                           \
        }                                                                      \
        {                                                                      \
            const float m1 = m12b.x, m2 = m12b.y;                              \
            const float m3 = m34b.x, m4 = m34b.y;                              \
            const float q1 = m1 * m1, q2 = m2 * m2, mm = m1 * m2;              \
            const float num = (2.f * mm + C1V) * (2.f * (m4 - mm) + C2V);      \
            const float den = (q1 + q2 + C1V) * (((m3 - q1) - q2) + C2V);      \
            acc += num * __builtin_amdgcn_rcpf(den);                           \
        }                                                                      \
    }

    f2 hs12[NS][2];                          // ring: [slot][col] {mu_r, mu_d}
    f2 hs34[NS][2];                          // ring: [slot][col] {E_rr+dd, E_rd}
    float acc = 0.0f;

    // prologue: rows 0..5 in flight (slots 0..5)
#pragma unroll
    for (int r = 0; r < LA; ++r) STAGE(o0 + r, r)

#pragma unroll 1
    for (int rr = 0; rr < NR; rr += NS) {
#pragma unroll
        for (int S = 0; S < NS / 2; ++S) {
            const int klin = rr + 2 * S;     // even; NR even -> klin+1 valid too
            if (klin < NR) {                 // block-uniform
                // stage rows klin+6, klin+7 (clamped tail -> dead slots)
                {
                    int ra = klin + 6; if (ra > NR - 1) ra = NR - 1;
                    int rb = klin + 7; if (rb > NR - 1) rb = NR - 1;
                    STAGE(o0 + ra, (2 * S + 6) % NS)
                    STAGE(o0 + rb, (2 * S + 7) % NS)
                }
                // exact per-wave wait: rows klin, klin+1 landed
                // (steady in-flight 8 rows; allow 6 -> 30/24 loads)
                if (!w3) asm volatile("s_waitcnt vmcnt(30)" ::: "memory");
                else     asm volatile("s_waitcnt vmcnt(24)" ::: "memory");

                f4v q0[6], q1[6];
                {
                    const f4v* rp0 = region + ((2 * S)     % NS) * slotf4 + rl;
                    const f4v* rp1 = region + ((2 * S + 1) % NS) * slotf4 + rl;
#pragma unroll
                    for (int j = 0; j < 6; ++j) q0[j] = rp0[j];
#pragma unroll
                    for (int j = 0; j < 6; ++j) q1[j] = rp1[j];
                }

                HPASS(q0, (2 * S) % NS)
                // V for row klin (output o = klin-10); -10 === +2 (mod 12)
                if (klin >= WSZ - 1 && (o0 + klin - (WSZ - 1)) < olim && active)
                    VPASS((2 * S + 2) % NS)

                HPASS(q1, (2 * S + 1) % NS)
                if (klin + 1 >= WSZ - 1 && (o0 + klin + 1 - (WSZ - 1)) < olim && active)
                    VPASS((2 * S + 3) % NS)
            }
        }
    }
#undef STAGE
#undef HPASS
#undef VPASS

    // ---- block reduction -> one atomicAdd per block ----
#pragma unroll
    for (int off = 32; off > 0; off >>= 1) acc += __shfl_down(acc, off, 64);
    if (lane == 0) wred[wave] = acc;
    __syncthreads();
    if (tid == 0) {
        const float tot = (wred[0] + wred[1]) + (wred[2] + wred[3]);
        atomicAdd(out + img / 3, tot * inv_n);
    }
}

extern "C" void kernel_launch(void* const* d_in, const int* in_sizes, int n_in,
                              void* d_out, int out_size, void* d_ws, size_t ws_size,
                              hipStream_t stream) {
    const float* raw = (const float*)d_in[0];
    const float* dst = (const float*)d_in[1];
    float* out = (float*)d_out;

    hipMemsetAsync(out, 0, (size_t)out_size * sizeof(float), stream);

    WinArg wa;
    double g[WSZ], s = 0.0;
    for (int i = 0; i < WSZ; ++i) {
        double ax = (double)i - (double)(WSZ - 1) / 2.0;
        g[i] = exp(-(ax * ax) / (2.0 * 1.5 * 1.5));
        s += g[i];
    }
    for (int i = 0; i < WSZ; ++i) wa.w[i] = (float)(g[i] / s);

    const float inv_n = (float)(1.0 / (3.0 * (double)OSZ * (double)OSZ));

    dim3 grid(NCHUNK, 48);
    ssim_ilp2<<<grid, NT, 0, stream>>>(raw, dst, out, wa, inv_n);
}

// Round 19
// 62.056 us; speedup vs baseline: 1.0330x; 1.0039x over previous
//
#include <hip/hip_runtime.h>
#include <math.h>

// SSIM (16,3,512,512) fp32, 11x11 separable Gaussian, VALID -> per-batch mean [16].
//
// Round-19: EXACT round-16 kernel (best: 59.4us) with ONE change: the work
// decomposition. Grid 768 (3 blocks/CU over 2 resident slots -> 2-epoch
// makespan for 1.5 epochs of work = 25% tail idle) becomes grid 1008
// (CH_OUT 32->24, NCHUNK 21): ~4 blocks/CU over 2 slots -> 2 epochs of
// T(34-row) blocks = 0.81x makespan at +6% halo row work.
//  - Each wave owns a 128-output-col strip (2 cols/thread) and stages its own
//    rows via global_load_lds; per-wave vmcnt(24) is the only synchronization.
//  - Channel-interleaved LDS float4(r,d,r,d); packed fp32 math (v_pk_fma_f32
//    via __builtin_elementwise_fma), {mu_r,mu_d}/{E_rr+dd,E_rd} as f32x2.
//  - 255x scaling cancels: C1 = 1e-4, C2 = 9e-4 on [0,1] data.

#define WSZ 11
#define IMG 512
#define OSZ 502
#define NT  256
#define CH_OUT 24
#define NCHUNK 21        // 21*24 = 504 >= 502
#define NSLOT 11
#define LA 6             // lookahead rows

struct WinArg { float w[WSZ]; };

typedef float f2 __attribute__((ext_vector_type(2)));
typedef float f4v __attribute__((ext_vector_type(4)));

typedef const __attribute__((address_space(1))) unsigned int* gp_t;
typedef __attribute__((address_space(3))) unsigned int* sp_t;

#define C1V 1.0e-4f
#define C2V 9.0e-4f

__device__ __forceinline__ void pkfma(f2& acc, f2 a, f2 b) {
    acc = __builtin_elementwise_fma(a, b, acc);   // v_pk_fma_f32
}

__global__ __launch_bounds__(NT, 3) void ssim_ep(
    const float* __restrict__ rawp, const float* __restrict__ dstp,
    float* __restrict__ out, WinArg wa, float inv_n)
{
    // waves 0-2: 11 slots x 80 float4 (880 f4 each); wave 3: 11 x 64 (704 f4)
    __shared__ f4v srow[3344];               // 53504 B
    __shared__ float wred[NT / 64];

    const int tid  = threadIdx.x;
    const int lane = tid & 63;
    const int wave = tid >> 6;
    const int chunk = blockIdx.x;
    const int img   = blockIdx.y;

    const int o0    = chunk * CH_OUT;
    const int olim  = min(o0 + CH_OUT, OSZ);
    const int rlast = min(o0 + CH_OUT + WSZ - 2, IMG - 1);
    const int NR    = rlast - o0 + 1;        // 34 (32 for last chunk)

    const bool w3     = (wave == 3);
    const int  nch    = w3 ? 4 : 5;          // DMA chunks per row (wave-uniform)
    const int  slotf4 = w3 ? 64 : 80;        // float4 per slot (wave-uniform)
    f4v* region = srow + wave * 880;         // wave 3 -> 2640, uses 704 f4
    const int  rl     = (w3 && lane > 58) ? 58 : lane;   // read clamp
    const bool active = !(w3 && lane > 58);

    const size_t ibase = (size_t)img * (size_t)(IMG * IMG);
    // lane parity -> channel; (lane>>1) -> col within 32-col chunk
    const float* lane_base = ((lane & 1) ? dstp : rawp) + ibase
                           + (size_t)(wave * 128 + (lane >> 1));

    // packed weights (compiler hoists / rematerializes as it prefers)
    f2 wv[WSZ];
#pragma unroll
    for (int j = 0; j < WSZ; ++j) { wv[j].x = wa.w[j]; wv[j].y = wa.w[j]; }

#define STAGE(ROW, SLOT)                                                       \
    {                                                                          \
        const float* _s = lane_base + (size_t)(ROW) * IMG;                     \
        float* _d = (float*)(region + (SLOT) * slotf4);                        \
        _Pragma("unroll")                                                      \
        for (int _c = 0; _c < 5; ++_c) {                                       \
            if (_c < nch)                                                      \
                __builtin_amdgcn_global_load_lds(                              \
                    (gp_t)(const void*)(_s + 32 * _c),                         \
                    (sp_t)(void*)(_d + 64 * _c), 4, 0, 0);                     \
        }                                                                      \
    }

    f2 hs12[WSZ][2];                         // ring: [slot][col] {mu_r, mu_d}
    f2 hs34[WSZ][2];                         // ring: [slot][col] {E_rr+dd, E_rd}
    float acc = 0.0f;

    // prologue: rows 0..LA-1 in flight (slots 0..5)
#pragma unroll
    for (int r = 0; r < LA; ++r) STAGE(o0 + r, r)

#pragma unroll 1
    for (int rr = 0; rr < NR; rr += WSZ) {
#pragma unroll
        for (int k = 0; k < WSZ; ++k) {
            const int klin = rr + k;
            if (klin < NR) {                 // block-uniform
                // stage row klin+LA (clamped tail restage lands in dead slot)
                {
                    int rs = klin + LA; if (rs > NR - 1) rs = NR - 1;
                    STAGE(o0 + rs, (k + LA) % NSLOT)
                }
                // per-wave wait: guarantees row klin's loads complete
                asm volatile("s_waitcnt vmcnt(24)" ::: "memory");

                f4v q[6];
                {
                    const f4v* rp = region + k * slotf4 + rl;
#pragma unroll
                    for (int j = 0; j < 6; ++j) q[j] = rp[j];
                }

                // ---- H-pass, 2 cols, packed channels ----
                f2 s12a = {0.f, 0.f}, s34a = {0.f, 0.f};
                f2 s12b = {0.f, 0.f}, s34b = {0.f, 0.f};
#pragma unroll
                for (int e = 0; e < 12; ++e) {
                    const f2 rd = (e & 1) ? q[e >> 1].zw : q[e >> 1].xy;
                    const f2 rr2 = rd * rd;                // v_pk_mul_f32
                    f2 sp;                                 // (r^2+d^2, r*d)
                    sp.x = rr2.x + rr2.y;
                    sp.y = rd.x * rd.y;
                    if (e < 11) {            // col a tap e
                        pkfma(s12a, wv[e], rd);
                        pkfma(s34a, wv[e], sp);
                    }
                    if (e >= 1) {            // col b tap e-1
                        pkfma(s12b, wv[e - 1], rd);
                        pkfma(s34b, wv[e - 1], sp);
                    }
                }
                hs12[k][0] = s12a; hs34[k][0] = s34a;
                hs12[k][1] = s12b; hs34[k][1] = s34b;

                // ---- V-pass + SSIM ----
                const int o = o0 + klin - (WSZ - 1);
                if (klin >= WSZ - 1 && o < olim && active) {
                    f2 m12a = {0.f, 0.f}, m34a = {0.f, 0.f};
                    f2 m12b = {0.f, 0.f}, m34b = {0.f, 0.f};
#pragma unroll
                    for (int i = 0; i < WSZ; ++i) {
                        const int s = (k + 1 + i) % WSZ;   // static after unroll
                        pkfma(m12a, wv[i], hs12[s][0]);
                        pkfma(m34a, wv[i], hs34[s][0]);
                        pkfma(m12b, wv[i], hs12[s][1]);
                        pkfma(m34b, wv[i], hs34[s][1]);
                    }
                    {
                        const float m1 = m12a.x, m2 = m12a.y;
                        const float m3 = m34a.x, m4 = m34a.y;
                        const float q1 = m1 * m1, q2 = m2 * m2, mm = m1 * m2;
                        const float num = (2.f * mm + C1V) * (2.f * (m4 - mm) + C2V);
                        const float den = (q1 + q2 + C1V) * (((m3 - q1) - q2) + C2V);
                        acc += num * __builtin_amdgcn_rcpf(den);
                    }
                    {
                        const float m1 = m12b.x, m2 = m12b.y;
                        const float m3 = m34b.x, m4 = m34b.y;
                        const float q1 = m1 * m1, q2 = m2 * m2, mm = m1 * m2;
                        const float num = (2.f * mm + C1V) * (2.f * (m4 - mm) + C2V);
                        const float den = (q1 + q2 + C1V) * (((m3 - q1) - q2) + C2V);
                        acc += num * __builtin_amdgcn_rcpf(den);
                    }
                }
            }
        }
    }
#undef STAGE

    // ---- block reduction -> one atomicAdd per block ----
#pragma unroll
    for (int off = 32; off > 0; off >>= 1) acc += __shfl_down(acc, off, 64);
    if (lane == 0) wred[wave] = acc;
    __syncthreads();
    if (tid == 0) {
        const float tot = (wred[0] + wred[1]) + (wred[2] + wred[3]);
        atomicAdd(out + img / 3, tot * inv_n);
    }
}

extern "C" void kernel_launch(void* const* d_in, const int* in_sizes, int n_in,
                              void* d_out, int out_size, void* d_ws, size_t ws_size,
                              hipStream_t stream) {
    const float* raw = (const float*)d_in[0];
    const float* dst = (const float*)d_in[1];
    float* out = (float*)d_out;

    hipMemsetAsync(out, 0, (size_t)out_size * sizeof(float), stream);

    WinArg wa;
    double g[WSZ], s = 0.0;
    for (int i = 0; i < WSZ; ++i) {
        double ax = (double)i - (double)(WSZ - 1) / 2.0;
        g[i] = exp(-(ax * ax) / (2.0 * 1.5 * 1.5));
        s += g[i];
    }
    for (int i = 0; i < WSZ; ++i) wa.w[i] = (float)(g[i] / s);

    const float inv_n = (float)(1.0 / (3.0 * (double)OSZ * (double)OSZ));

    dim3 grid(NCHUNK, 48);
    ssim_ep<<<grid, NT, 0, stream>>>(raw, dst, out, wa, inv_n);
}